// Round 1
// baseline (142.725 us; speedup 1.0000x reference)
//
#include <hip/hip_runtime.h>

#define B_IMG 8
#define A_TOTAL 120000
#define C_CLS 80
#define M_ANN 32
#define APB 256      // anchors per block
#define THREADS 256

// ws layout (floats): [0..7] c_sum per image, [8..15] r_sum, [16..23] npos
__global__ void init_ws_kernel(float* __restrict__ ws) {
    int i = threadIdx.x;
    if (i < 3 * B_IMG) ws[i] = 0.0f;
}

__global__ __launch_bounds__(THREADS) void focal_main_kernel(
    const float* __restrict__ cls,      // (B, A, C)
    const float* __restrict__ reg,      // (B, A, 4)
    const float* __restrict__ anchors,  // (A, 4)  [y1,x1,y2,x2]
    const float* __restrict__ ann,      // (B, M, 5) [x1,y1,x2,y2,class]
    float* __restrict__ ws)
{
    __shared__ float ann_s[M_ANN * 5];
    __shared__ float area_s[M_ANN];
    __shared__ int   state_s[APB];          // -1 ignore, -2 negative, >=0 pos class
    __shared__ float red_c[4], red_r[4], red_n[4];

    const int b   = blockIdx.y;
    const int a0  = blockIdx.x * APB;
    const int tid = threadIdx.x;
    const int nA  = min(APB, A_TOTAL - a0);

    if (tid < M_ANN * 5) ann_s[tid] = ann[b * M_ANN * 5 + tid];
    __syncthreads();
    if (tid < M_ANN) {
        float bx1 = ann_s[tid * 5 + 0], by1 = ann_s[tid * 5 + 1];
        float bx2 = ann_s[tid * 5 + 2], by2 = ann_s[tid * 5 + 3];
        area_s[tid] = (bx2 - bx1) * (by2 - by1);
    }
    __syncthreads();

    // ---- Phase 1: per-anchor IoU argmax, state, and GIoU for positives ----
    float r_acc = 0.0f;
    float n_acc = 0.0f;
    int   st    = -1;
    if (tid < nA) {
        const int a = a0 + tid;
        float4 anc = ((const float4*)anchors)[a];
        float ay1 = anc.x, ax1 = anc.y, ay2 = anc.z, ax2 = anc.w;
        float area_a = (ay2 - ay1) * (ax2 - ax1);
        float best = -1.0f;
        int   barg = 0;
        #pragma unroll
        for (int j = 0; j < M_ANN; ++j) {
            float bx1 = ann_s[j * 5 + 0], by1 = ann_s[j * 5 + 1];
            float bx2 = ann_s[j * 5 + 2], by2 = ann_s[j * 5 + 3];
            float iw = fminf(ax2, bx2) - fmaxf(ax1, bx1);
            float ih = fminf(ay2, by2) - fmaxf(ay1, by1);
            iw = fmaxf(iw, 0.0f);
            ih = fmaxf(ih, 0.0f);
            float inter = iw * ih;
            float ua = fmaxf(area_a + area_s[j] - inter, 1e-8f);
            float iou = inter / ua;
            if (iou > best) { best = iou; barg = j; }   // strict > == first-argmax
        }
        if (best >= 0.5f) {
            st    = (int)ann_s[barg * 5 + 4];
            n_acc = 1.0f;
            // regression GIoU loss for this positive anchor
            float4 rg = ((const float4*)reg)[(size_t)b * A_TOTAL + a];
            float ty = rg.x, tx = rg.y, th = rg.z, tw = rg.w;
            float aw = ax2 - ax1, ah = ay2 - ay1;
            float acx = ax1 + 0.5f * aw, acy = ay1 + 0.5f * ah;
            float pcx = tx * aw + acx, pcy = ty * ah + acy;
            float pw = __expf(tw) * aw, ph = __expf(th) * ah;
            float px1 = fmaxf(pcx - 0.5f * pw, 0.0f);
            float py1 = fmaxf(pcy - 0.5f * ph, 0.0f);
            float px2 = fmaxf(pcx + 0.5f * pw, 0.0f);
            float py2 = fmaxf(pcy + 0.5f * ph, 0.0f);
            float gx1 = fmaxf(ann_s[barg * 5 + 0], 0.0f);
            float gy1 = fmaxf(ann_s[barg * 5 + 1], 0.0f);
            float gx2 = fmaxf(ann_s[barg * 5 + 2], 0.0f);
            float gy2 = fmaxf(ann_s[barg * 5 + 3], 0.0f);
            float iw2 = fmaxf(fminf(px2, gx2) - fmaxf(px1, gx1), 0.0f);
            float ih2 = fmaxf(fminf(py2, gy2) - fmaxf(py1, gy1), 0.0f);
            float inter = iw2 * ih2;
            float area_p = fmaxf((px2 - px1) * (py2 - py1), 1e-6f);
            float area_g = fmaxf((gx2 - gx1) * (gy2 - gy1), 1e-6f);
            float uni = area_p + area_g - inter;
            float iou2 = inter / (uni + 1e-7f);
            float wc = fmaxf(fmaxf(px2, gx2) - fminf(px1, gx1), 1e-6f);
            float hc = fmaxf(fmaxf(py2, gy2) - fminf(py1, gy1), 1e-6f);
            float area_c = wc * hc;
            float giou = fminf(fmaxf(iou2 - (area_c - uni) / (area_c + 1e-7f), -1.0f), 1.0f);
            r_acc = 1.0f - giou;
        } else if (best < 0.4f) {
            st = -2;
        }
    }
    state_s[tid] = st;
    __syncthreads();

    // ---- Phase 2: classification focal loss, coalesced float4 over (nA x 80) ----
    float c_acc = 0.0f;
    const float4* cp = (const float4*)(cls + ((size_t)b * A_TOTAL + a0) * C_CLS);
    const int nf4 = nA * (C_CLS / 4);   // 80 % 4 == 0: each float4 is inside one anchor row
    for (int i = tid; i < nf4; i += THREADS) {
        float4 v = cp[i];
        int anchor = i / 20;            // 20 float4 per anchor
        int cb = (i - anchor * 20) * 4; // first class in this float4
        int s = state_s[anchor];
        if (s != -1) {
            float vv[4] = {v.x, v.y, v.z, v.w};
            #pragma unroll
            for (int k = 0; k < 4; ++k) {
                float c = fminf(fmaxf(vv[k], 5e-4f), 1.0f - 5e-4f);
                bool t1 = (s == cb + k);            // false for s==-2 (negative)
                float x   = t1 ? (1.0f - c) : c;    // focal base
                float af  = t1 ? 0.25f : 0.75f;     // alpha factor
                float arg = t1 ? c : (1.0f - c);    // log argument
                c_acc += af * x * x * (-__logf(arg));
            }
        }
    }

    // ---- Block reduction + per-image atomics ----
    #pragma unroll
    for (int o = 32; o > 0; o >>= 1) {
        c_acc += __shfl_down(c_acc, o);
        r_acc += __shfl_down(r_acc, o);
        n_acc += __shfl_down(n_acc, o);
    }
    int wid = tid >> 6;
    if ((tid & 63) == 0) { red_c[wid] = c_acc; red_r[wid] = r_acc; red_n[wid] = n_acc; }
    __syncthreads();
    if (tid == 0) {
        float cs = red_c[0] + red_c[1] + red_c[2] + red_c[3];
        float rs = red_r[0] + red_r[1] + red_r[2] + red_r[3];
        float ns = red_n[0] + red_n[1] + red_n[2] + red_n[3];
        atomicAdd(&ws[b], cs);
        atomicAdd(&ws[B_IMG + b], rs);
        atomicAdd(&ws[2 * B_IMG + b], ns);
    }
}

__global__ void finalize_kernel(const float* __restrict__ ws, float* __restrict__ out) {
    if (threadIdx.x == 0) {
        float c = 0.0f, r = 0.0f;
        for (int b = 0; b < B_IMG; ++b) {
            float n = ws[2 * B_IMG + b];
            c += ws[b] / fmaxf(n, 1.0f);
            r += (n > 0.0f) ? (ws[B_IMG + b] / fmaxf(n, 1.0f)) : 0.0f;
        }
        c *= (1.0f / B_IMG);
        r *= (1.0f / B_IMG);
        out[0] = c + r;
        out[1] = c;
        out[2] = r;
    }
}

extern "C" void kernel_launch(void* const* d_in, const int* in_sizes, int n_in,
                              void* d_out, int out_size, void* d_ws, size_t ws_size,
                              hipStream_t stream) {
    const float* cls     = (const float*)d_in[0];
    const float* reg     = (const float*)d_in[1];
    const float* anchors = (const float*)d_in[2];
    const float* ann     = (const float*)d_in[3];
    float* ws  = (float*)d_ws;
    float* out = (float*)d_out;

    hipLaunchKernelGGL(init_ws_kernel, dim3(1), dim3(64), 0, stream, ws);
    dim3 grid((A_TOTAL + APB - 1) / APB, B_IMG);
    hipLaunchKernelGGL(focal_main_kernel, grid, dim3(THREADS), 0, stream,
                       cls, reg, anchors, ann, ws);
    hipLaunchKernelGGL(finalize_kernel, dim3(1), dim3(64), 0, stream, ws, out);
}

// Round 2
// 138.145 us; speedup vs baseline: 1.0332x; 1.0332x over previous
//
#include <hip/hip_runtime.h>

#define B_IMG 8
#define A_TOTAL 120000
#define C_CLS 80
#define M_ANN 32
#define APB 256      // anchors per block
#define THREADS 256
#define NEG075LN2 (-0.51986038542f)   // -0.75 * ln(2)

// ws layout (floats): [0..7] c_sum per image, [8..15] r_sum, [16..23] npos
__global__ void init_ws_kernel(float* __restrict__ ws) {
    int i = threadIdx.x;
    if (i < 3 * B_IMG) ws[i] = 0.0f;
}

__global__ __launch_bounds__(THREADS) void focal_main_kernel(
    const float* __restrict__ cls,      // (B, A, C)
    const float* __restrict__ reg,      // (B, A, 4)
    const float* __restrict__ anchors,  // (A, 4)  [y1,x1,y2,x2]
    const float* __restrict__ ann,      // (B, M, 5) [x1,y1,x2,y2,class]
    float* __restrict__ ws)
{
    __shared__ float m_s[APB];          // per-anchor multiplier: 0 (ignore) or -0.75*ln2
    __shared__ float red_c[4], red_r[4], red_n[4];

    const int b   = blockIdx.y;
    const int a0  = blockIdx.x * APB;
    const int tid = threadIdx.x;
    const int nA  = min(APB, A_TOTAL - a0);
    const float* __restrict__ annb = ann + b * (M_ANN * 5);  // uniform -> s_load

    float r_acc = 0.0f, n_acc = 0.0f, c_acc = 0.0f;
    float mval  = 0.0f;

    // ---- Phase 1: IoU argmax (division-free), state, GIoU + focal correction for positives ----
    if (tid < nA) {
        const int a = a0 + tid;
        float4 anc = ((const float4*)anchors)[a];
        float ay1 = anc.x, ax1 = anc.y, ay2 = anc.z, ax2 = anc.w;
        float area_a = (ay2 - ay1) * (ax2 - ax1);
        float binter = 0.0f, bua = 1.0f;
        int   barg = 0;
        #pragma unroll
        for (int j = 0; j < M_ANN; ++j) {
            float bx1 = annb[j * 5 + 0], by1 = annb[j * 5 + 1];
            float bx2 = annb[j * 5 + 2], by2 = annb[j * 5 + 3];
            float iw = fmaxf(fminf(ax2, bx2) - fmaxf(ax1, bx1), 0.0f);
            float ih = fmaxf(fminf(ay2, by2) - fmaxf(ay1, by1), 0.0f);
            float inter = iw * ih;
            float ua = fmaxf(area_a + (bx2 - bx1) * (by2 - by1) - inter, 1e-8f);
            // iou_j > iou_best  <=>  inter_j * ua_best > inter_best * ua_j  (all >= 0)
            bool gt = inter * bua > binter * ua;
            binter = gt ? inter : binter;
            bua    = gt ? ua    : bua;
            barg   = gt ? j     : barg;   // strict > keeps FIRST max (matches jnp.argmax)
        }
        bool pos = binter >= 0.5f * bua;
        bool neg = binter <  0.4f * bua;
        mval = (pos || neg) ? NEG075LN2 : 0.0f;   // ignore band -> 0

        if (pos) {
            n_acc = 1.0f;
            int k = (int)annb[barg * 5 + 4];
            // focal correction: true class uses pos formula, phase 2 applies neg formula
            float cv = cls[((size_t)b * A_TOTAL + a) * C_CLS + k];
            float c  = fminf(fmaxf(cv, 5e-4f), 1.0f - 5e-4f);
            float omc = 1.0f - c;
            c_acc += 0.25f * omc * omc * (-__logf(c))
                   - 0.75f * c * c * (-__logf(omc));

            // regression GIoU loss
            float4 rg = ((const float4*)reg)[(size_t)b * A_TOTAL + a];
            float ty = rg.x, tx = rg.y, th = rg.z, tw = rg.w;
            float aw = ax2 - ax1, ah = ay2 - ay1;
            float acx = ax1 + 0.5f * aw, acy = ay1 + 0.5f * ah;
            float pcx = tx * aw + acx, pcy = ty * ah + acy;
            float pw = __expf(tw) * aw, ph = __expf(th) * ah;
            float px1 = fmaxf(pcx - 0.5f * pw, 0.0f);
            float py1 = fmaxf(pcy - 0.5f * ph, 0.0f);
            float px2 = fmaxf(pcx + 0.5f * pw, 0.0f);
            float py2 = fmaxf(pcy + 0.5f * ph, 0.0f);
            float gx1 = fmaxf(annb[barg * 5 + 0], 0.0f);
            float gy1 = fmaxf(annb[barg * 5 + 1], 0.0f);
            float gx2 = fmaxf(annb[barg * 5 + 2], 0.0f);
            float gy2 = fmaxf(annb[barg * 5 + 3], 0.0f);
            float iw2 = fmaxf(fminf(px2, gx2) - fmaxf(px1, gx1), 0.0f);
            float ih2 = fmaxf(fminf(py2, gy2) - fmaxf(py1, gy1), 0.0f);
            float inter2 = iw2 * ih2;
            float area_p = fmaxf((px2 - px1) * (py2 - py1), 1e-6f);
            float area_g = fmaxf((gx2 - gx1) * (gy2 - gy1), 1e-6f);
            float uni = area_p + area_g - inter2;
            float iou2 = inter2 / (uni + 1e-7f);
            float wc = fmaxf(fmaxf(px2, gx2) - fminf(px1, gx1), 1e-6f);
            float hc = fmaxf(fmaxf(py2, gy2) - fminf(py1, gy1), 1e-6f);
            float area_c = wc * hc;
            float giou = fminf(fmaxf(iou2 - (area_c - uni) / (area_c + 1e-7f), -1.0f), 1.0f);
            r_acc = 1.0f - giou;
        }
    }
    m_s[tid] = (tid < nA) ? mval : 0.0f;
    __syncthreads();

    // ---- Phase 2: streaming focal loss (neg formula, multiplier per anchor) ----
    const float4* __restrict__ cp =
        (const float4*)(cls + ((size_t)b * A_TOTAL + a0) * C_CLS);
    const int nf4 = nA * (C_CLS / 4);
    for (int i = tid; i < nf4; i += THREADS) {
        float4 v = cp[i];
        unsigned anchor = (unsigned)i / 20u;   // 20 float4 per anchor
        float m = m_s[anchor];
        float s = 0.0f;
        {
            float c = fminf(fmaxf(v.x, 5e-4f), 1.0f - 5e-4f);
            s = fmaf(c * c, __log2f(1.0f - c), s);
            c = fminf(fmaxf(v.y, 5e-4f), 1.0f - 5e-4f);
            s = fmaf(c * c, __log2f(1.0f - c), s);
            c = fminf(fmaxf(v.z, 5e-4f), 1.0f - 5e-4f);
            s = fmaf(c * c, __log2f(1.0f - c), s);
            c = fminf(fmaxf(v.w, 5e-4f), 1.0f - 5e-4f);
            s = fmaf(c * c, __log2f(1.0f - c), s);
        }
        c_acc = fmaf(m, s, c_acc);   // m = -0.75*ln2 (active) or 0 (ignore)
    }

    // ---- Block reduction + per-image atomics ----
    #pragma unroll
    for (int o = 32; o > 0; o >>= 1) {
        c_acc += __shfl_down(c_acc, o);
        r_acc += __shfl_down(r_acc, o);
        n_acc += __shfl_down(n_acc, o);
    }
    int wid = tid >> 6;
    if ((tid & 63) == 0) { red_c[wid] = c_acc; red_r[wid] = r_acc; red_n[wid] = n_acc; }
    __syncthreads();
    if (tid == 0) {
        float cs = red_c[0] + red_c[1] + red_c[2] + red_c[3];
        float rs = red_r[0] + red_r[1] + red_r[2] + red_r[3];
        float ns = red_n[0] + red_n[1] + red_n[2] + red_n[3];
        atomicAdd(&ws[b], cs);
        atomicAdd(&ws[B_IMG + b], rs);
        atomicAdd(&ws[2 * B_IMG + b], ns);
    }
}

__global__ void finalize_kernel(const float* __restrict__ ws, float* __restrict__ out) {
    if (threadIdx.x == 0) {
        float c = 0.0f, r = 0.0f;
        for (int b = 0; b < B_IMG; ++b) {
            float n = ws[2 * B_IMG + b];
            c += ws[b] / fmaxf(n, 1.0f);
            r += (n > 0.0f) ? (ws[B_IMG + b] / fmaxf(n, 1.0f)) : 0.0f;
        }
        c *= (1.0f / B_IMG);
        r *= (1.0f / B_IMG);
        out[0] = c + r;
        out[1] = c;
        out[2] = r;
    }
}

extern "C" void kernel_launch(void* const* d_in, const int* in_sizes, int n_in,
                              void* d_out, int out_size, void* d_ws, size_t ws_size,
                              hipStream_t stream) {
    const float* cls     = (const float*)d_in[0];
    const float* reg     = (const float*)d_in[1];
    const float* anchors = (const float*)d_in[2];
    const float* ann     = (const float*)d_in[3];
    float* ws  = (float*)d_ws;
    float* out = (float*)d_out;

    hipLaunchKernelGGL(init_ws_kernel, dim3(1), dim3(64), 0, stream, ws);
    dim3 grid((A_TOTAL + APB - 1) / APB, B_IMG);
    hipLaunchKernelGGL(focal_main_kernel, grid, dim3(THREADS), 0, stream,
                       cls, reg, anchors, ann, ws);
    hipLaunchKernelGGL(finalize_kernel, dim3(1), dim3(64), 0, stream, ws, out);
}